// Round 2
// baseline (14575.304 us; speedup 1.0000x reference)
//
#include <hip/hip_runtime.h>
#include <hip/hip_bf16.h>

// VQ-VAE forward, MI355X round 2: fp32 I/O (per reference), bf16 intermediates.
// Outputs (fp32): x_recon [32,3,256,256] flat, then loss scalar at [6291456].

using bf16 = __hip_bfloat16;

#define BATCH 32
#define NE    512
#define ED    32

__device__ __forceinline__ float ldf(const float* p, long i) { return p[i]; }
__device__ __forceinline__ float ldf(const bf16*  p, long i) { return __bfloat162float(p[i]); }
__device__ __forceinline__ void  stf(float* p, long i, float v) { p[i] = v; }
__device__ __forceinline__ void  stf(bf16*  p, long i, float v) { p[i] = __float2bfloat16(v); }

// ---------------- direct conv (encoder): NCHW, weights OIHW fp32 ------------
template<typename TI, typename TO,
         int CIN,int COUT,int K,int S,int P,int HIN,int HOUT,bool RELU>
__global__ __launch_bounds__(256) void conv_k(const TI* __restrict__ in,
    const float* __restrict__ w, const float* __restrict__ bias,
    TO* __restrict__ out) {
  __shared__ float wsm[CIN*K*K];
  const int co = blockIdx.y, n = blockIdx.z;
  for (int t = threadIdx.x; t < CIN*K*K; t += 256)
    wsm[t] = w[(long)co*CIN*K*K + t];
  __syncthreads();
  const int sp = blockIdx.x*256 + threadIdx.x;
  if (sp >= HOUT*HOUT) return;
  const int oy = sp / HOUT, ox = sp % HOUT;
  float acc = bias[co];
  const long nb = (long)n*CIN*HIN*HIN;
  for (int ci = 0; ci < CIN; ++ci) {
    const long cb = nb + (long)ci*HIN*HIN;
    #pragma unroll
    for (int ky = 0; ky < K; ++ky) {
      const int iy = oy*S - P + ky;
      if (iy < 0 || iy >= HIN) continue;
      #pragma unroll
      for (int kx = 0; kx < K; ++kx) {
        const int ix = ox*S - P + kx;
        if (ix < 0 || ix >= HIN) continue;
        acc = fmaf(ldf(in, cb + (long)iy*HIN + ix), wsm[(ci*K + ky)*K + kx], acc);
      }
    }
  }
  if (RELU) acc = fmaxf(acc, 0.f);
  stf(out, ((long)n*COUT + co)*HOUT*HOUT + sp, acc);
}

// ------------- transposed conv (decoder), gather form -----------------------
// torch ConvTranspose2d weight layout (CIN, COUT, K, K), fp32.
template<typename TI, typename TO,
         int CIN,int COUT,int K,int S,int P,int HIN,int HOUT,bool RELU>
__global__ __launch_bounds__(256) void convt_k(const TI* __restrict__ in,
    const float* __restrict__ w, const float* __restrict__ bias,
    TO* __restrict__ out) {
  __shared__ float wsm[CIN*K*K];
  const int co = blockIdx.y, n = blockIdx.z;
  for (int t = threadIdx.x; t < CIN*K*K; t += 256) {
    const int ci = t / (K*K), r = t % (K*K);
    wsm[t] = w[((long)ci*COUT + co)*K*K + r];
  }
  __syncthreads();
  const int sp = blockIdx.x*256 + threadIdx.x;
  if (sp >= HOUT*HOUT) return;
  const int oy = sp / HOUT, ox = sp % HOUT;
  float acc = bias[co];
  const long nb = (long)n*CIN*HIN*HIN;
  #pragma unroll
  for (int ky = 0; ky < K; ++ky) {
    const int ty = oy + P - ky;
    if (ty < 0 || (ty % S) != 0) continue;
    const int iy = ty / S;
    if (iy >= HIN) continue;
    #pragma unroll
    for (int kx = 0; kx < K; ++kx) {
      const int tx = ox + P - kx;
      if (tx < 0 || (tx % S) != 0) continue;
      const int ix = tx / S;
      if (ix >= HIN) continue;
      const long sb = nb + (long)iy*HIN + ix;
      const int  wb = ky*K + kx;
      for (int ci = 0; ci < CIN; ++ci)
        acc = fmaf(ldf(in, sb + (long)ci*HIN*HIN), wsm[ci*K*K + wb], acc);
    }
  }
  if (RELU) acc = fmaxf(acc, 0.f);
  stf(out, ((long)n*COUT + co)*HOUT*HOUT + sp, acc);
}

// ------------- vector quantizer: argmin over 512 codes (2 LDS chunks) -------
__global__ __launch_bounds__(256) void vq_k(const float* __restrict__ z,
    const float* __restrict__ embed, float* __restrict__ zq,
    float* __restrict__ partial) {
  __shared__ float esm[256*ED];   // 32 KB: one 256-code chunk
  __shared__ float enorm[256];
  __shared__ float red[256];
  const int p  = blockIdx.x*256 + threadIdx.x;     // 0..131071
  const int n  = p >> 12, yx = p & 4095;
  const long zb = (long)n*ED*4096 + yx;
  float zf[ED];
  #pragma unroll
  for (int c = 0; c < ED; ++c) zf[c] = z[zb + (long)c*4096];
  float best = 1e30f; int bi = 0;
  for (int chunk = 0; chunk < 2; ++chunk) {
    __syncthreads();                                // prev chunk fully consumed
    for (int t = threadIdx.x; t < 256*ED; t += 256)
      esm[t] = embed[chunk*256*ED + t];
    __syncthreads();
    {
      float s = 0.f;
      #pragma unroll
      for (int c = 0; c < ED; ++c) s = fmaf(esm[threadIdx.x*ED + c], esm[threadIdx.x*ED + c], s);
      enorm[threadIdx.x] = s;
    }
    __syncthreads();
    for (int j = 0; j < 256; ++j) {
      float dot = 0.f;
      #pragma unroll
      for (int c = 0; c < ED; ++c) dot = fmaf(esm[j*ED + c], zf[c], dot);
      const float d = enorm[j] - 2.f*dot;            // +|z|^2 const: argmin same
      if (d < best) { best = d; bi = chunk*256 + j; }
    }
  }
  float se = 0.f;
  #pragma unroll
  for (int c = 0; c < ED; ++c) {
    const float e = embed[(long)bi*ED + c];          // exact fp32 codeword
    zq[zb + (long)c*4096] = e;
    const float df = e - zf[c];
    se = fmaf(df, df, se);
  }
  red[threadIdx.x] = se; __syncthreads();
  for (int s = 128; s > 0; s >>= 1) {
    if (threadIdx.x < s) red[threadIdx.x] += red[threadIdx.x + s];
    __syncthreads();
  }
  if (threadIdx.x == 0) partial[blockIdx.x] = red[0];
}

__global__ __launch_bounds__(512) void loss_k(const float* __restrict__ part,
                                              float* __restrict__ out) {
  __shared__ float red[512];
  const int t = threadIdx.x;
  red[t] = part[t]; __syncthreads();
  for (int s = 256; s > 0; s >>= 1) {
    if (t < s) red[t] += red[t + s];
    __syncthreads();
  }
  if (t == 0) out[0] = red[0] * (1.25f / (131072.f * 32.f));
}

extern "C" void kernel_launch(void* const* d_in, const int* in_sizes, int n_in,
                              void* d_out, int out_size, void* d_ws, size_t ws_size,
                              hipStream_t stream) {
  const float* x   = (const float*)d_in[0];
  const float* ew1 = (const float*)d_in[1];  const float* eb1 = (const float*)d_in[2];
  const float* ew2 = (const float*)d_in[3];  const float* eb2 = (const float*)d_in[4];
  const float* ew3 = (const float*)d_in[5];  const float* eb3 = (const float*)d_in[6];
  const float* emb = (const float*)d_in[7];
  const float* dw1 = (const float*)d_in[8];  const float* db1 = (const float*)d_in[9];
  const float* dw2 = (const float*)d_in[10]; const float* db2 = (const float*)d_in[11];
  const float* dw3 = (const float*)d_in[12]; const float* db3 = (const float*)d_in[13];
  float* out = (float*)d_out;

  // workspace layout (bytes):
  //   [0,            67108864)  h1 bf16 32x64x128x128   (reused for d2)
  //   [67108864,    100663296)  h2 bf16 32x128x64x64    (reused for d1)
  //   [100663296,   117440512)  z  f32  32x32x64x64
  //   [117440512,   134217728)  zq f32  32x32x64x64
  //   [134217728,   134219776)  loss partials (512 f32)
  uint8_t* w8 = (uint8_t*)d_ws;
  bf16*  h1   = (bf16*)(w8);
  bf16*  h2   = (bf16*)(w8 + 67108864);
  float* z    = (float*)(w8 + 100663296);
  float* zq   = (float*)(w8 + 117440512);
  float* part = (float*)(w8 + 134217728);
  bf16*  d1   = h2;   // h2 dead after conv3
  bf16*  d2   = h1;   // h1 dead after conv2

  // encoder
  conv_k<float,bf16, 3,64,4,2,1,256,128,true>
      <<<dim3(64,64,BATCH),256,0,stream>>>(x, ew1, eb1, h1);
  conv_k<bf16,bf16, 64,128,4,2,1,128,64,true>
      <<<dim3(16,128,BATCH),256,0,stream>>>(h1, ew2, eb2, h2);
  conv_k<bf16,float, 128,32,3,1,1,64,64,true>
      <<<dim3(16,32,BATCH),256,0,stream>>>(h2, ew3, eb3, z);
  // vector quantizer + loss
  vq_k<<<dim3(512),256,0,stream>>>(z, emb, zq, part);
  loss_k<<<dim3(1),512,0,stream>>>(part, out + 6291456);
  // decoder
  convt_k<float,bf16, 32,128,3,1,1,64,64,true>
      <<<dim3(16,128,BATCH),256,0,stream>>>(zq, dw1, db1, d1);
  convt_k<bf16,bf16, 128,64,4,2,1,64,128,true>
      <<<dim3(64,64,BATCH),256,0,stream>>>(d1, dw2, db2, d2);
  convt_k<bf16,float, 64,3,4,2,1,128,256,false>
      <<<dim3(256,3,BATCH),256,0,stream>>>(d2, dw3, db3, out);
}

// Round 3
// 668.621 us; speedup vs baseline: 21.7991x; 21.7991x over previous
//
#include <hip/hip_runtime.h>

// VQ-VAE forward, MI355X round 3: NHWC + MFMA implicit GEMM for the 4 big
// layers; direct kernels for conv1 / convt3 / VQ. fp32 I/O, bf16 intermediates.

typedef __attribute__((ext_vector_type(8))) short     short8;
typedef __attribute__((ext_vector_type(8))) __bf16    bf16x8;
typedef __attribute__((ext_vector_type(4))) float     f32x4;

#define BATCH 32

__device__ __forceinline__ float b2f(unsigned short b) {
  union { unsigned u; float f; } v; v.u = ((unsigned)b) << 16; return v.f;
}
__device__ __forceinline__ unsigned short f2b(float f) {  // round-to-nearest-even
  union { float f; unsigned u; } v; v.f = f;
  unsigned r = v.u + 0x7FFF + ((v.u >> 16) & 1);
  return (unsigned short)(r >> 16);
}

// ---------------- weight prep: reorganize to [tap][co][ci] bf16 -------------
__global__ __launch_bounds__(256) void prep2_k(const float* __restrict__ w,
                                               unsigned short* __restrict__ wq) {
  const int i = blockIdx.x*256 + threadIdx.x;                 // 131072 exact
  const int ci = i & 63, co = (i >> 6) & 127, t = i >> 13;
  wq[i] = f2b(w[(co*64 + ci)*16 + t]);                        // ew2 OIHW(128,64,4,4)
}
__global__ __launch_bounds__(256) void prep3_k(const float* __restrict__ w,
                                               unsigned short* __restrict__ wq) {
  const int i = blockIdx.x*256 + threadIdx.x;                 // 36864 exact
  const int ci = i & 127, co = (i >> 7) & 31, t = i >> 12;
  wq[i] = f2b(w[(co*128 + ci)*9 + t]);                        // ew3 OIHW(32,128,3,3)
}
__global__ __launch_bounds__(256) void prep4_k(const float* __restrict__ w,
                                               unsigned short* __restrict__ wq) {
  const int i = blockIdx.x*256 + threadIdx.x;                 // 36864 exact
  const int ci = i & 31, co = (i >> 5) & 127, t = i >> 12;
  wq[i] = f2b(w[(ci*128 + co)*9 + (8 - t)]);                  // dw1(32,128,3,3), flipped
}
__global__ __launch_bounds__(256) void prep5_k(const float* __restrict__ w,
                                               unsigned short* __restrict__ wq) {
  const int i = blockIdx.x*256 + threadIdx.x;                 // 131072 exact
  const int ci = i & 127, co = (i >> 7) & 63, t = (i >> 13) & 3, p = i >> 15;
  const int ky = 2 - 2*(t >> 1) + (1 - (p >> 1));
  const int kx = 2 - 2*(t & 1)  + (1 - (p & 1));
  wq[i] = f2b(w[(ci*64 + co)*16 + ky*4 + kx]);                // dw2(128,64,4,4)
}

// --------- MFMA implicit-GEMM conv: NHWC in -> NHWC out (64x64 spatial) -----
// M = 32*64*64 = 131072 output positions, block tile 128M x COUT, 4 waves.
// A (im2col) and B (weights [tap][co][ci]) staged per (tap, 32-ci chunk).
template<int CIN,int COUT,int HIN,int S,int KW,int NTAPS,int OSTRIDE,int P,
         bool PARITY,bool RELU,bool INF32,bool OUTF32>
__global__ __launch_bounds__(256) void mconv_k(const void* __restrict__ in_,
    const unsigned short* __restrict__ wq_, const float* __restrict__ bias,
    void* __restrict__ out_) {
  constexpr int NF  = COUT / 16;
  constexpr int NCH = CIN / 32;
  __shared__ short Al[128*40];      // 128 rows x 32 k, stride 40 (80B, 16B-mult)
  __shared__ short Bl[COUT*40];
  int py = 0, px = 0, PY = P, PX = P;
  const unsigned short* wq = wq_;
  if (PARITY) {
    py = blockIdx.y >> 1; px = blockIdx.y & 1;
    PY = 1 - py; PX = 1 - px;
    wq += blockIdx.y * (NTAPS*COUT*CIN);
  }
  const int m0 = blockIdx.x * 128;
  const int w  = threadIdx.x >> 6, l = threadIdx.x & 63;
  const int lm = l & 15, lk = l >> 4;
  f32x4 acc[2][NF];
  #pragma unroll
  for (int mi = 0; mi < 2; ++mi)
    #pragma unroll
    for (int ni = 0; ni < NF; ++ni) acc[mi][ni] = (f32x4)0.0f;

  for (int tap = 0; tap < NTAPS; ++tap) {
    const int ky = tap / KW, kx = tap % KW;
    for (int ch = 0; ch < NCH; ++ch) {
      const int c0 = ch * 32;
      __syncthreads();                       // prev iter frag reads done
      // ---- A stage: 128 rows x 64B, 4 lanes/row ----
      for (int s = threadIdx.x; s < 512; s += 256) {
        const int row = s >> 2, part = s & 3;
        const int m = m0 + row;
        const int n = m >> 12, oy = (m >> 6) & 63, ox = m & 63;
        const int iy = oy*S - PY + ky, ix = ox*S - PX + kx;
        short8 v = (short8)(short)0;
        if (iy >= 0 && iy < HIN && ix >= 0 && ix < HIN) {
          const int base = ((n*HIN + iy)*HIN + ix)*CIN + c0 + part*8;
          if (INF32) {
            const float* pf = (const float*)in_ + base;
            const f32x4 f0 = *(const f32x4*)pf;
            const f32x4 f1 = *(const f32x4*)(pf + 4);
            #pragma unroll
            for (int j = 0; j < 4; ++j) {
              v[j]     = (short)f2b(f0[j]);
              v[j + 4] = (short)f2b(f1[j]);
            }
          } else {
            v = *(const short8*)((const unsigned short*)in_ + base);
          }
        }
        *(short8*)&Al[row*40 + part*8] = v;
      }
      // ---- B stage: COUT rows x 64B ----
      for (int s = threadIdx.x; s < COUT*4; s += 256) {
        const int co = s >> 2, part = s & 3;
        *(short8*)&Bl[co*40 + part*8] =
            *(const short8*)(wq + (tap*COUT + co)*CIN + c0 + part*8);
      }
      __syncthreads();
      // ---- fragments + MFMA ----
      short8 av[2];
      #pragma unroll
      for (int mi = 0; mi < 2; ++mi)
        av[mi] = *(const short8*)&Al[(w*32 + mi*16 + lm)*40 + lk*8];
      #pragma unroll
      for (int ni = 0; ni < NF; ++ni) {
        const short8 bv = *(const short8*)&Bl[(ni*16 + lm)*40 + lk*8];
        #pragma unroll
        for (int mi = 0; mi < 2; ++mi)
          acc[mi][ni] = __builtin_amdgcn_mfma_f32_16x16x32_bf16(
              __builtin_bit_cast(bf16x8, av[mi]),
              __builtin_bit_cast(bf16x8, bv),
              acc[mi][ni], 0, 0, 0);
      }
    }
  }
  // ---- epilogue: C/D layout col=lane&15 (n), row=(lane>>4)*4+reg (m) ----
  #pragma unroll
  for (int ni = 0; ni < NF; ++ni) {
    const int co = ni*16 + lm;
    const float bv = bias[co];
    #pragma unroll
    for (int mi = 0; mi < 2; ++mi) {
      #pragma unroll
      for (int r = 0; r < 4; ++r) {
        const int ml = w*32 + mi*16 + lk*4 + r;
        const int m  = m0 + ml;
        float vv = acc[mi][ni][r] + bv;
        if (RELU) vv = fmaxf(vv, 0.f);
        int off;
        if (OSTRIDE == 1) {
          off = m*COUT + co;
        } else {
          const int n = m >> 12, oy = (m >> 6) & 63, ox = m & 63;
          off = ((n*128 + oy*2 + py)*128 + ox*2 + px)*COUT + co;
        }
        if (OUTF32) ((float*)out_)[off] = vv;
        else ((unsigned short*)out_)[off] = f2b(vv);
      }
    }
  }
}

// ---------------- conv1: x NCHW fp32 (3ch) -> h1 NHWC bf16 [32,128,128,64] --
__global__ __launch_bounds__(256) void conv1_k(const float* __restrict__ x,
    const float* __restrict__ w, const float* __restrict__ bias,
    unsigned short* __restrict__ out) {
  __shared__ float wl[64*48];
  __shared__ float bl[64];
  for (int t = threadIdx.x; t < 3072; t += 256) wl[t] = w[t];
  if (threadIdx.x < 64) bl[threadIdx.x] = bias[threadIdx.x];
  __syncthreads();
  const int n  = blockIdx.x >> 6, oy = (blockIdx.x & 63)*2 + (threadIdx.x >> 7);
  const int ox = threadIdx.x & 127;
  float xin[48];
  #pragma unroll
  for (int ci = 0; ci < 3; ++ci)
    #pragma unroll
    for (int ky = 0; ky < 4; ++ky) {
      const int iy = oy*2 - 1 + ky;
      #pragma unroll
      for (int kx = 0; kx < 4; ++kx) {
        const int ix = ox*2 - 1 + kx;
        float v = 0.f;
        if (iy >= 0 && iy < 256 && ix >= 0 && ix < 256)
          v = x[((n*3 + ci)*256 + iy)*256 + ix];
        xin[ci*16 + ky*4 + kx] = v;
      }
    }
  const int ob = ((n*128 + oy)*128 + ox)*64;
  #pragma unroll
  for (int cb = 0; cb < 8; ++cb) {
    short8 sv;
    #pragma unroll
    for (int j = 0; j < 8; ++j) {
      const int co = cb*8 + j;
      float a = bl[co];
      #pragma unroll
      for (int q = 0; q < 12; ++q) {
        const f32x4 wv = *(const f32x4*)&wl[co*48 + q*4];
        a = fmaf(xin[q*4+0], wv[0], a);
        a = fmaf(xin[q*4+1], wv[1], a);
        a = fmaf(xin[q*4+2], wv[2], a);
        a = fmaf(xin[q*4+3], wv[3], a);
      }
      sv[j] = (short)f2b(fmaxf(a, 0.f));
    }
    *(short8*)&out[ob + cb*8] = sv;
  }
}

// ------- VQ: z fp32 [131072,32] -> zq fp32 [131072,32] + loss partials ------
__global__ __launch_bounds__(256) void vq_k(const float* __restrict__ z,
    const float* __restrict__ embed, float* __restrict__ zq,
    float* __restrict__ partial) {
  __shared__ float esm[256*32];
  __shared__ float enorm[256];
  __shared__ float red[256];
  const int p = blockIdx.x*256 + threadIdx.x;   // 0..131071
  float zf[32];
  #pragma unroll
  for (int c = 0; c < 32; ++c) zf[c] = z[p*32 + c];
  float best = 1e30f; int bi = 0;
  for (int chunk = 0; chunk < 2; ++chunk) {
    __syncthreads();
    for (int t = threadIdx.x; t < 256*32; t += 256)
      esm[t] = embed[chunk*256*32 + t];
    __syncthreads();
    {
      float s = 0.f;
      #pragma unroll
      for (int c = 0; c < 32; ++c)
        s = fmaf(esm[threadIdx.x*32 + c], esm[threadIdx.x*32 + c], s);
      enorm[threadIdx.x] = s;
    }
    __syncthreads();
    for (int j = 0; j < 256; ++j) {
      float dot = 0.f;
      #pragma unroll
      for (int c = 0; c < 32; ++c) dot = fmaf(esm[j*32 + c], zf[c], dot);
      const float d = enorm[j] - 2.f*dot;
      if (d < best) { best = d; bi = chunk*256 + j; }
    }
  }
  float se = 0.f;
  #pragma unroll
  for (int c = 0; c < 32; ++c) {
    const float e = embed[bi*32 + c];
    zq[p*32 + c] = e;
    const float df = e - zf[c];
    se = fmaf(df, df, se);
  }
  red[threadIdx.x] = se; __syncthreads();
  for (int s = 128; s > 0; s >>= 1) {
    if (threadIdx.x < s) red[threadIdx.x] += red[threadIdx.x + s];
    __syncthreads();
  }
  if (threadIdx.x == 0) partial[blockIdx.x] = red[0];
}

__global__ __launch_bounds__(512) void loss_k(const float* __restrict__ part,
                                              float* __restrict__ out) {
  __shared__ float red[512];
  const int t = threadIdx.x;
  red[t] = part[t]; __syncthreads();
  for (int s = 256; s > 0; s >>= 1) {
    if (t < s) red[t] += red[t + s];
    __syncthreads();
  }
  if (t == 0) out[0] = red[0] * (1.25f / (131072.f * 32.f));
}

// -------- convt3: d2 NHWC bf16 [32,128,128,64] -> x_recon NCHW fp32 ---------
__global__ __launch_bounds__(256) void convt3_k(const unsigned short* __restrict__ in,
    const float* __restrict__ w, const float* __restrict__ bias,
    float* __restrict__ out) {
  __shared__ float wl[3072];
  __shared__ float bl[3];
  for (int t = threadIdx.x; t < 3072; t += 256) wl[t] = w[t];  // dw3(64,3,4,4)
  if (threadIdx.x < 3) bl[threadIdx.x] = bias[threadIdx.x];
  __syncthreads();
  const int n = blockIdx.x >> 8, oy = blockIdx.x & 255;
  const int px = threadIdx.x >> 7, xq = threadIdx.x & 127;   // wave-uniform px
  const int py = oy & 1, yq = oy >> 1;
  const int ox = xq*2 + px;
  float a0 = bl[0], a1 = bl[1], a2 = bl[2];
  #pragma unroll
  for (int a = 0; a < 2; ++a) {
    const int iy = yq - (1 - py) + a;
    if (iy < 0 || iy >= 128) continue;
    const int ky = 2 - 2*a + (1 - py);
    #pragma unroll
    for (int b = 0; b < 2; ++b) {
      const int ix = xq - (1 - px) + b;
      if (ix < 0 || ix >= 128) continue;
      const int kx = 2 - 2*b + (1 - px);
      const int t = ky*4 + kx;
      const unsigned short* ip = in + ((n*128 + iy)*128 + ix)*64;
      #pragma unroll
      for (int c8 = 0; c8 < 8; ++c8) {
        const short8 v8 = *(const short8*)(ip + c8*8);
        #pragma unroll
        for (int j = 0; j < 8; ++j) {
          const int ci = c8*8 + j;
          const float v = b2f((unsigned short)v8[j]);
          a0 = fmaf(v, wl[(ci*3 + 0)*16 + t], a0);
          a1 = fmaf(v, wl[(ci*3 + 1)*16 + t], a1);
          a2 = fmaf(v, wl[(ci*3 + 2)*16 + t], a2);
        }
      }
    }
  }
  const int sp = oy*256 + ox;
  out[(n*3 + 0)*65536 + sp] = a0;
  out[(n*3 + 1)*65536 + sp] = a1;
  out[(n*3 + 2)*65536 + sp] = a2;
}

extern "C" void kernel_launch(void* const* d_in, const int* in_sizes, int n_in,
                              void* d_out, int out_size, void* d_ws, size_t ws_size,
                              hipStream_t stream) {
  const float* x   = (const float*)d_in[0];
  const float* ew1 = (const float*)d_in[1];  const float* eb1 = (const float*)d_in[2];
  const float* ew2 = (const float*)d_in[3];  const float* eb2 = (const float*)d_in[4];
  const float* ew3 = (const float*)d_in[5];  const float* eb3 = (const float*)d_in[6];
  const float* emb = (const float*)d_in[7];
  const float* dw1 = (const float*)d_in[8];  const float* db1 = (const float*)d_in[9];
  const float* dw2 = (const float*)d_in[10]; const float* db2 = (const float*)d_in[11];
  const float* dw3 = (const float*)d_in[12]; const float* db3 = (const float*)d_in[13];
  float* out = (float*)d_out;

  // ws layout (bytes), total 134,219,776 (== round-2 footprint):
  //   h1  NHWC bf16 [32,128,128,64]  @ 0          (67108864)   -> reused as d2
  //   h2  NHWC bf16 [32, 64, 64,128] @ 67108864   (33554432)   -> reused as d1
  //   z   f32  [131072,32]           @ 100663296  (16777216)
  //   zq  f32  [131072,32]           @ 117440512  (16777216)
  //   part f32 [512]                 @ 134217728  (2048)
  //   wq2/wq3 overlaid in zq region (dead until vq); wq4/wq5 in z region
  //   (written after vq, when z is dead).
  uint8_t* w8 = (uint8_t*)d_ws;
  unsigned short* h1 = (unsigned short*)w8;
  unsigned short* h2 = (unsigned short*)(w8 + 67108864);
  float* z   = (float*)(w8 + 100663296);
  float* zq  = (float*)(w8 + 117440512);
  float* part = (float*)(w8 + 134217728);
  unsigned short* wq2 = (unsigned short*)(w8 + 117440512);            // 262144 B
  unsigned short* wq3 = (unsigned short*)(w8 + 117440512 + 262144);   // 73728 B
  unsigned short* wq4 = (unsigned short*)(w8 + 100663296);            // 73728 B
  unsigned short* wq5 = (unsigned short*)(w8 + 100663296 + 73728);    // 262144 B
  unsigned short* d1 = h2;
  unsigned short* d2 = h1;

  // encoder weight prep (into zq region, consumed before vq writes zq)
  prep2_k<<<dim3(512),256,0,stream>>>(ew2, wq2);
  prep3_k<<<dim3(144),256,0,stream>>>(ew3, wq3);
  // encoder
  conv1_k<<<dim3(2048),256,0,stream>>>(x, ew1, eb1, h1);
  mconv_k<64,128,128,2,4,16,1,1,false,true,false,false>
      <<<dim3(1024),256,0,stream>>>(h1, wq2, eb2, h2);
  mconv_k<128,32,64,1,3,9,1,1,false,true,false,true>
      <<<dim3(1024),256,0,stream>>>(h2, wq3, eb3, z);
  // VQ + loss
  vq_k<<<dim3(512),256,0,stream>>>(z, emb, zq, part);
  loss_k<<<dim3(1),512,0,stream>>>(part, out + 6291456);
  // decoder weight prep (into z region, dead after vq)
  prep4_k<<<dim3(144),256,0,stream>>>(dw1, wq4);
  prep5_k<<<dim3(512),256,0,stream>>>(dw2, wq5);
  // decoder
  mconv_k<32,128,64,1,3,9,1,1,false,true,true,false>
      <<<dim3(1024),256,0,stream>>>(zq, wq4, db1, d1);
  mconv_k<128,64,64,1,2,4,2,0,true,true,false,false>
      <<<dim3(1024,4),256,0,stream>>>(d1, wq5, db2, d2);
  convt3_k<<<dim3(8192),256,0,stream>>>(d2, dw3, db3, out);
}